// Round 7
// baseline (283.703 us; speedup 1.0000x reference)
//
#include <hip/hip_runtime.h>
#include <hip/hip_bf16.h>
#include <hip/hip_cooperative_groups.h>

namespace cg = cooperative_groups;

#define B 4
#define T 4096
#define D 512
#define KKEEP 1024
#define RSQRT_D 0.044194173824159216f  // 1/sqrt(512)
#define NBLK 256
#define NTHR 512

// Monotone float->uint map: preserves total order.
__device__ __forceinline__ unsigned f2ord(float f) {
    unsigned u = __float_as_uint(f);
    return (u & 0x80000000u) ? ~u : (u | 0x80000000u);
}
__device__ __forceinline__ float ord2f(unsigned o) {
    return __uint_as_float((o & 0x80000000u) ? (o ^ 0x80000000u) : ~o);
}

// One cooperative kernel, 6 phases split by grid.sync().
// 256 blocks x 512 threads; LDS phases alias one 42KB buffer.
__global__ __launch_bounds__(NTHR) void k_fused(
    const float* __restrict__ h,  const float* __restrict__ Wq,
    const float* __restrict__ bq, const float* __restrict__ Wk,
    const float* __restrict__ bk, const float* __restrict__ Wv,
    const float* __restrict__ bv, float* __restrict__ out,
    float* __restrict__ qpart, float* __restrict__ wvec,
    float* __restrict__ cvec,  float* __restrict__ sc,
    unsigned* __restrict__ selI, float* __restrict__ selW,
    float* __restrict__ part)
{
    cg::grid_group grid = cg::this_grid();
    int blk = blockIdx.x, tid = threadIdx.x;
    int lane = tid & 63, wave = tid >> 6;  // 8 waves

    __shared__ __align__(16) unsigned char smem[42112];

    // ---- P1: qpart[b][z][j] = sum_{d in 64-chunk z} h[b,T-1,d] * Wq[d,j]
    // 32 blocks -> Wq's 1MB read spread wide (round-5 lesson).
    if (blk < 32) {
        int b = blk >> 3, z = blk & 7, d0 = z * 64;
        float* hs = (float*)smem;
        if (tid < 64) hs[tid] = h[((size_t)b * T + (T - 1)) * D + d0 + tid];
        __syncthreads();
        float acc = 0.f;
#pragma unroll 8
        for (int d = 0; d < 64; ++d) acc += hs[d] * Wq[(size_t)(d0 + d) * D + tid];
        qpart[(b * 8 + z) * D + tid] = acc;
    }
    grid.sync();

    // ---- P2: wvec[b][d] = rsqrtD * (Wk[d,:] . q);  cvec[b] = rsqrtD * (bk . q)
    if (blk < 32) {
        int b = blk >> 3, z = blk & 7;
        float* qs = (float*)smem;
        float s = 0.f;
#pragma unroll 8
        for (int z2 = 0; z2 < 8; ++z2) s += qpart[(b * 8 + z2) * D + tid];
        qs[tid] = s + bq[tid];
        __syncthreads();
        const float4* q4 = (const float4*)qs;
        for (int r = 0; r < 8; ++r) {
            int d = z * 64 + wave * 8 + r;
            const float4* w4 = (const float4*)(Wk + (size_t)d * D);
            float4 a = w4[lane], qa = q4[lane];
            float4 b4 = w4[lane + 64], qb = q4[lane + 64];
            float acc = a.x*qa.x + a.y*qa.y + a.z*qa.z + a.w*qa.w
                      + b4.x*qb.x + b4.y*qb.y + b4.z*qb.z + b4.w*qb.w;
            for (int off = 32; off; off >>= 1) acc += __shfl_down(acc, off);
            if (lane == 0) wvec[b * D + d] = acc * RSQRT_D;
        }
        if (z == 0 && wave == 0) {
            float a = 0.f;
            for (int k = lane; k < D; k += 64) a += bk[k] * qs[k];
            for (int off = 32; off; off >>= 1) a += __shfl_down(a, off);
            if (lane == 0) cvec[b] = a * RSQRT_D;
        }
    }
    grid.sync();

    // ---- P3: sc[b,s] = h[b,s,:] . wvec[b] + cvec[b]  (all 256 blocks, 64 rows each)
    {
        int b = blk >> 6, s0 = (blk & 63) * 64;
        float* wsv = (float*)smem;
        wsv[tid] = wvec[b * D + tid];
        __syncthreads();
        const float4* w4 = (const float4*)wsv;
        float cv = cvec[b];
        for (int r = 0; r < 8; ++r) {
            int s = s0 + wave * 8 + r;
            const float4* h4 = (const float4*)(h + ((size_t)b * T + s) * D);
            float4 a = h4[lane], wa = w4[lane];
            float4 b4 = h4[lane + 64], wb = w4[lane + 64];
            float acc = a.x*wa.x + a.y*wa.y + a.z*wa.z + a.w*wa.w
                      + b4.x*wb.x + b4.y*wb.y + b4.z*wb.z + b4.w*wb.w;
            for (int off = 32; off; off >>= 1) acc += __shfl_down(acc, off);
            if (lane == 0) sc[b * T + s] = acc + cv;
        }
    }
    grid.sync();

    // ---- P4: exact top-1024 radix select + softmax weights (blocks 0..3)
    if (blk < B) {
        int b = blk;
        unsigned* ordk = (unsigned*)smem;      // 4096 u32
        unsigned* tieI = ordk + T;             // 4096 u32
        unsigned* sI   = tieI + T;             // 1024 u32
        float*    sW   = (float*)(sI + KKEEP); // 1024 f32
        int*      hist = (int*)(sW + KKEEP);   // 256
        float*    red  = (float*)(hist + 256); // 8
        __shared__ unsigned sh_pv;
        __shared__ int sh_r, sh_cnt, sh_tiecnt;
        __shared__ float sh_max, sh_inv;

        float sv[8];
        float lmax = -INFINITY;
#pragma unroll
        for (int k = 0; k < 8; ++k) {
            int i = tid + k * NTHR;
            float v = sc[b * T + i];
            sv[k] = v;
            ordk[i] = f2ord(v);
            lmax = fmaxf(lmax, v);
        }
        for (int off = 32; off; off >>= 1) lmax = fmaxf(lmax, __shfl_down(lmax, off));
        if (lane == 0) red[wave] = lmax;
        __syncthreads();
        if (tid == 0) {
            float m = red[0];
            for (int w = 1; w < 8; ++w) m = fmaxf(m, red[w]);
            sh_max = m; sh_pv = 0; sh_r = KKEEP; sh_cnt = 0; sh_tiecnt = 0;
        }
        __syncthreads();

        for (int p = 24; p >= 0; p -= 8) {
            if (tid < 256) hist[tid] = 0;
            __syncthreads();
            unsigned pv = sh_pv;
#pragma unroll
            for (int k = 0; k < 8; ++k) {
                unsigned key = ordk[tid + k * NTHR];
                bool act = (p == 24) || ((key >> (p + 8)) == pv);
                if (act) atomicAdd(&hist[(key >> p) & 255], 1);
            }
            __syncthreads();
            if (tid < 64) {  // wave 0: suffix-scan 256 bins, locate rank r
                int r = sh_r;
                int c0 = hist[tid*4], c1 = hist[tid*4+1], c2 = hist[tid*4+2], c3 = hist[tid*4+3];
                int ssum = c0 + c1 + c2 + c3;
                int cum = ssum;
                for (int off = 1; off < 64; off <<= 1) {
                    int v = __shfl_down(cum, off);
                    if (tid + off < 64) cum += v;
                }
                int base = cum - ssum;
                if (base < r && r <= cum) {  // exactly one lane
                    int d, sg;
                    if (r <= base + c3)                { d = 3; sg = base; }
                    else if (r <= base + c3 + c2)      { d = 2; sg = base + c3; }
                    else if (r <= base + c3 + c2 + c1) { d = 1; sg = base + c3 + c2; }
                    else                               { d = 0; sg = base + c3 + c2 + c1; }
                    sh_pv = (pv << 8) | (unsigned)(tid * 4 + d);
                    sh_r = r - sg;
                }
            }
            __syncthreads();
        }

        unsigned vstar = sh_pv;
        int rtie = sh_r;
        float gmax = sh_max;

#pragma unroll
        for (int k = 0; k < 8; ++k) {
            int i = tid + k * NTHR;
            unsigned key = ordk[i];
            if (key > vstar) {
                int pos = atomicAdd(&sh_cnt, 1);
                sI[pos] = (unsigned)i;
                sW[pos] = __expf(sv[k] - gmax);
            } else if (key == vstar) {
                int pos = atomicAdd(&sh_tiecnt, 1);
                tieI[pos] = (unsigned)i;
            }
        }
        __syncthreads();

        int tcnt = sh_tiecnt;
        float tw = __expf(ord2f(vstar) - gmax);
        for (int t = tid; t < tcnt; t += NTHR) {
            unsigned my = tieI[t];
            int rank = 0;
            for (int o = 0; o < tcnt; ++o) rank += (tieI[o] < my);
            if (rank < rtie) {  // rtie smallest-index ties included
                int pos = atomicAdd(&sh_cnt, 1);
                sI[pos] = my;
                sW[pos] = tw;
            }
        }
        __syncthreads();

        float lsum = sW[tid] + sW[tid + NTHR];
        for (int off = 32; off; off >>= 1) lsum += __shfl_down(lsum, off);
        if (lane == 0) red[wave] = lsum;
        __syncthreads();
        if (tid == 0) {
            float ssum = 0.f;
            for (int w = 0; w < 8; ++w) ssum += red[w];
            sh_inv = 1.0f / ssum;
        }
        __syncthreads();
        selI[b * KKEEP + tid]        = sI[tid];
        selW[b * KKEEP + tid]        = sW[tid] * sh_inv;
        selI[b * KKEEP + tid + NTHR] = sI[tid + NTHR];
        selW[b * KKEEP + tid + NTHR] = sW[tid + NTHR] * sh_inv;
    }
    grid.sync();

    // ---- P5: part[b][y][:] = sum over 32 selected rows of w * h[b,idx,:]  (blocks 0..127)
    if (blk < 128) {
        int b = blk >> 5, y = blk & 31;
        float4* red4 = (float4*)smem;  // 512 float4 = 8KB
        int g = tid >> 7, l = tid & 127;
        int e0 = y * 32;
        float4 acc = make_float4(0.f, 0.f, 0.f, 0.f);
        for (int e = g; e < 32; e += 4) {
            unsigned s = selI[b * KKEEP + e0 + e];
            float w = selW[b * KKEEP + e0 + e];
            float4 v = ((const float4*)(h + ((size_t)b * T + s) * D))[l];
            acc.x += w * v.x; acc.y += w * v.y; acc.z += w * v.z; acc.w += w * v.w;
        }
        red4[tid] = acc;
        __syncthreads();
        if (tid < 128) {
            float4 a = red4[tid], b4 = red4[tid+128], c = red4[tid+256], d4 = red4[tid+384];
            float4 r = make_float4(a.x+b4.x+c.x+d4.x, a.y+b4.y+c.y+d4.y,
                                   a.z+b4.z+c.z+d4.z, a.w+b4.w+c.w+d4.w);
            ((float4*)part)[(b * 32 + y) * 128 + tid] = r;
        }
    }
    grid.sync();

    // ---- P6: out[b,j] = (sum_p part[b][p]) . Wv[:,j] + bv[j]  (blocks 0..3)
    if (blk < B) {
        int b = blk;
        float* wss = (float*)smem;
        float ssum = 0.f;
#pragma unroll 8
        for (int p = 0; p < 32; ++p) ssum += part[(size_t)(b * 32 + p) * D + tid];
        wss[tid] = ssum;
        __syncthreads();
        float acc = bv[tid];
#pragma unroll 4
        for (int d = 0; d < D; ++d) acc += wss[d] * Wv[(size_t)d * D + tid];
        out[b * D + tid] = acc;
    }
}

// ---------------------------------------------------------------------------
extern "C" void kernel_launch(void* const* d_in, const int* in_sizes, int n_in,
                              void* d_out, int out_size, void* d_ws, size_t ws_size,
                              hipStream_t stream) {
    const float* h  = (const float*)d_in[0];
    const float* Wq = (const float*)d_in[1];
    const float* bq = (const float*)d_in[2];
    const float* Wk = (const float*)d_in[3];
    const float* bk = (const float*)d_in[4];
    const float* Wv = (const float*)d_in[5];
    const float* bv = (const float*)d_in[6];
    float* out = (float*)d_out;

    float* ws = (float*)d_ws;
    float* qpart   = ws;                       // B*8*D  = 16384
    float* wvec    = ws + 16384;               // B*D    = 2048
    float* cvec    = ws + 18432;               // B (pad 64)
    float* sc      = ws + 18496;               // B*T    = 16384
    unsigned* selI = (unsigned*)(ws + 34880);  // B*KKEEP = 4096
    float* selW    = ws + 38976;               // B*KKEEP = 4096
    float* part    = ws + 43072;               // B*32*D = 65536

    void* args[] = {(void*)&h, (void*)&Wq, (void*)&bq, (void*)&Wk, (void*)&bk,
                    (void*)&Wv, (void*)&bv, (void*)&out, (void*)&qpart,
                    (void*)&wvec, (void*)&cvec, (void*)&sc, (void*)&selI,
                    (void*)&selW, (void*)&part};
    hipLaunchCooperativeKernel((const void*)k_fused, dim3(NBLK), dim3(NTHR),
                               args, 0, stream);
}